// Round 7
// baseline (161.956 us; speedup 1.0000x reference)
//
#include <hip/hip_runtime.h>

#define DIM 256
#define NA 16
#define NE 4
#define KTOT 288   // 16 atoms + 256 latent + 16 zero pad
#define KC 96      // K per third

typedef __attribute__((ext_vector_type(8))) short short8;
typedef __attribute__((ext_vector_type(4))) float f32x4;

static __device__ __forceinline__ ushort f2bf(float f) {
  union { float f; unsigned int u; } v; v.f = f;
  unsigned int r = (v.u + 0x7FFFu + ((v.u >> 16) & 1u)) >> 16;
  return (ushort)r;
}

static __device__ __forceinline__ float bf2f(ushort s) {
  union { unsigned int u; float f; } v; v.u = ((unsigned int)s) << 16;
  return v.f;
}

static __device__ __forceinline__ unsigned cvtpk(float lo, float hi) {
  unsigned r;
  asm("v_cvt_pk_bf16_f32 %0, %1, %2" : "=v"(r) : "v"(lo), "v"(hi));
  return r;
}

// async global->LDS DMA, 16B per lane; lds dest must be wave-uniform (HW adds lane*16)
static __device__ __forceinline__ void gll16(const void* g, void* l) {
  __builtin_amdgcn_global_load_lds((const __attribute__((address_space(1))) void*)g,
                                   (__attribute__((address_space(3))) void*)l, 16, 0, 0);
}

// ---------------- prep 1: h = relu(latent@W1+b1)@W2+b2 ; build G = [atoms|h|0] bf16
__global__ __launch_bounds__(256) void prep_h_kernel(
    const float* __restrict__ latent, const float* __restrict__ atoms,
    const float* __restrict__ W1, const float* __restrict__ b1,
    const float* __restrict__ W2, const float* __restrict__ b2,
    float* __restrict__ h_out, ushort* __restrict__ G_out) {
  __shared__ float lat[8][DIM];
  __shared__ float t1[8][DIM];
  const int b = blockIdx.x >> 5, i0 = (blockIdx.x & 31) * 8;
  const int k = threadIdx.x;
  #pragma unroll
  for (int r = 0; r < 8; ++r) lat[r][k] = latent[(b*256 + i0 + r) * DIM + k];
  __syncthreads();
  float acc[8];
  #pragma unroll
  for (int r = 0; r < 8; ++r) acc[r] = b1[k];
  for (int c = 0; c < DIM; c += 4) {
    float w0 = W1[(c+0)*DIM + k], w1 = W1[(c+1)*DIM + k];
    float w2 = W1[(c+2)*DIM + k], w3 = W1[(c+3)*DIM + k];
    #pragma unroll
    for (int r = 0; r < 8; ++r) {
      const float4 l4 = *reinterpret_cast<const float4*>(&lat[r][c]);
      acc[r] += l4.x*w0 + l4.y*w1 + l4.z*w2 + l4.w*w3;
    }
  }
  #pragma unroll
  for (int r = 0; r < 8; ++r) t1[r][k] = fmaxf(acc[r], 0.f);
  __syncthreads();
  #pragma unroll
  for (int r = 0; r < 8; ++r) acc[r] = b2[k];
  for (int c = 0; c < DIM; c += 4) {
    float w0 = W2[(c+0)*DIM + k], w1 = W2[(c+1)*DIM + k];
    float w2 = W2[(c+2)*DIM + k], w3 = W2[(c+3)*DIM + k];
    #pragma unroll
    for (int r = 0; r < 8; ++r) {
      const float4 l4 = *reinterpret_cast<const float4*>(&t1[r][c]);
      acc[r] += l4.x*w0 + l4.y*w1 + l4.z*w2 + l4.w*w3;
    }
  }
  #pragma unroll
  for (int r = 0; r < 8; ++r) {
    int row = b*256 + i0 + r;
    h_out[row*DIM + k] = acc[r];
    G_out[row*KTOT + NA + k] = f2bf(acc[r]);
  }
  if (k < NA) {
    #pragma unroll
    for (int r = 0; r < 8; ++r) {
      int row = b*256 + i0 + r;
      G_out[row*KTOT + k] = f2bf(atoms[row*NA + k]);
      G_out[row*KTOT + 272 + k] = 0;
    }
  }
}

// ---------------- prep 2: W3T[k][c] = bf16(W3[1+c][k]) zero-padded to 288
__global__ __launch_bounds__(256) void prep_w3t_kernel(
    const float* __restrict__ W3, ushort* __restrict__ W3T) {
  const int kk = blockIdx.x, c = threadIdx.x;
  W3T[kk*KTOT + c] = (c < 272) ? f2bf(W3[(1+c)*DIM + kk]) : (ushort)0;
  if (c < 32) {
    int c2 = 256 + c;
    W3T[kk*KTOT + c2] = (c2 < 272) ? f2bf(W3[(1+c2)*DIM + kk]) : (ushort)0;
  }
}

// ---------------- main: per (b,i) workgroup
// Z^T[n][j] = sum_c (g_i[c]*W3T[n][c]) * G[j][c] via MFMA.
// af (A-operand) built COOPERATIVELY into LDS once per WG per K-third:
// kills W3T L2 re-reads (1.8GB -> 295MB) and register spills.
// All LDS slabs tiled-linear 256B subtile units: conflict-free by construction.
__global__ __attribute__((amdgpu_flat_work_group_size(512,512), amdgpu_waves_per_eu(2,2)))
void edge_main_kernel(
    const float* __restrict__ positions, const float* __restrict__ atoms,
    const float* __restrict__ W3, const float* __restrict__ b3,
    const float* __restrict__ W4, const float* __restrict__ b4,
    const float* __restrict__ h_ws, const ushort* __restrict__ G,
    const ushort* __restrict__ W3T, float* __restrict__ out) {
  __shared__ union UU {
    char bufs[2][49152];          // double-buffered G slab (48KB each)
    float partial[4][256][4];     // epilogue partials (16KB), used after final barrier
  } u;
  __shared__ char af_lds[49152];  // af slab for current K-third (48KB)
  __shared__ float g_lds[KTOT];
  __shared__ float dist_lds[256];

  const int b = blockIdx.x >> 8, i = blockIdx.x & 255;
  const int tid = threadIdx.x;
  const int lane = tid & 63, w = tid >> 6;
  const int wn = w & 3;           // n-quadrant: 64 cols each
  const int wj = w >> 2;          // j-half: 128 rows each
  const int c15 = lane & 15, hi = lane >> 4;
  const int rowbase = b*256 + i;

  if (tid < KTOT)
    g_lds[tid] = (tid < NA) ? atoms[rowbase*NA + tid]
               : (tid < 272 ? h_ws[rowbase*DIM + (tid - NA)] : 0.f);
  if (tid < 256) {
    const float* pi = &positions[rowbase*3];
    const float* pj = &positions[(b*256 + tid)*3];
    float dx = pi[0]-pj[0], dy = pi[1]-pj[1], dz = pi[2]-pj[2];
    float d2 = dx*dx + dy*dy + dz*dz;
    dist_lds[tid] = d2 > 0.f ? sqrtf(d2) : 0.f;
  }

  // ---- async stage of one K-third into bufs[bufi] (6 x 16B DMA per lane)
  // G layout: subtile st = jtile*12 + ks (256B = 16 rows x 16B), ks = c-octet
  auto stage = [&](int bufi, int t3) {
    char* base = &u.bufs[bufi][w * 6144];
    #pragma unroll
    for (int ch = 0; ch < 6; ++ch) {
      int st = w*24 + ch*4 + hi;
      int rb = st / 12, ks = st - rb*12;
      const ushort* src = &G[(size_t)(b*256 + rb*16 + c15) * KTOT + t3*KC + ks*8];
      gll16(src, base + ch*1024);
    }
  };

  f32x4 acc[4][8];
  #pragma unroll
  for (int nt = 0; nt < 4; ++nt)
    #pragma unroll
    for (int jt = 0; jt < 8; ++jt) { acc[nt][jt].x=0.f; acc[nt][jt].y=0.f; acc[nt][jt].z=0.f; acc[nt][jt].w=0.f; }

  stage(0, 0);
  __syncthreads();   // g_lds/dist ready + stage(0) DMA drained

  int cur = 0;
  #pragma unroll
  for (int t3 = 0; t3 < 3; ++t3) {
    // ---- build af[t3] cooperatively into LDS: af[n][c] = bf16(g[c]*W3T[n][c])
    // same subtile layout as G: st2 = ntile*12 + ks; each thread-span = 16B
    #pragma unroll
    for (int s = 0; s < 6; ++s) {
      int id = s*512 + tid;
      int st2 = id >> 4, c15r = id & 15;
      int ntile = st2 / 12, ks = st2 - ntile*12;
      int n = ntile*16 + c15r;
      union { ushort us[8]; short8 s8; } wv;
      wv.s8 = *reinterpret_cast<const short8*>(&W3T[(size_t)n*KTOT + t3*KC + ks*8]);
      const float* gp = &g_lds[t3*KC + ks*8];
      float4 ga = *reinterpret_cast<const float4*>(gp);
      float4 gb = *reinterpret_cast<const float4*>(gp + 4);
      union { unsigned uu[4]; short8 s8; } pk;
      pk.uu[0] = cvtpk(bf2f(wv.us[0])*ga.x, bf2f(wv.us[1])*ga.y);
      pk.uu[1] = cvtpk(bf2f(wv.us[2])*ga.z, bf2f(wv.us[3])*ga.w);
      pk.uu[2] = cvtpk(bf2f(wv.us[4])*gb.x, bf2f(wv.us[5])*gb.y);
      pk.uu[3] = cvtpk(bf2f(wv.us[6])*gb.z, bf2f(wv.us[7])*gb.w);
      *reinterpret_cast<short8*>(&af_lds[st2*256 + c15r*16]) = pk.s8;
    }
    __syncthreads();                 // af[t3] visible (no DMA in flight here)
    if (t3 < 2) stage(cur ^ 1, t3 + 1);   // prefetch next third; drains at NEXT barrier
    // ---- MFMA: per wave 36 ds_read_b128 + 96 MFMA over this third
    const char* bp = u.bufs[cur];
    #pragma unroll
    for (int kc2 = 0; kc2 < 3; ++kc2) {
      short8 afr[4];
      #pragma unroll
      for (int nt = 0; nt < 4; ++nt)
        afr[nt] = *reinterpret_cast<const short8*>(
            &af_lds[((wn*4 + nt)*12 + kc2*4)*256 + lane*16]);
      #pragma unroll
      for (int jt = 0; jt < 8; ++jt) {
        short8 bb = *reinterpret_cast<const short8*>(
            bp + ((wj*8 + jt)*12 + kc2*4)*256 + lane*16);
        acc[0][jt] = __builtin_amdgcn_mfma_f32_16x16x32_bf16(afr[0], bb, acc[0][jt], 0, 0, 0);
        acc[1][jt] = __builtin_amdgcn_mfma_f32_16x16x32_bf16(afr[1], bb, acc[1][jt], 0, 0, 0);
        acc[2][jt] = __builtin_amdgcn_mfma_f32_16x16x32_bf16(afr[2], bb, acc[2][jt], 0, 0, 0);
        acc[3][jt] = __builtin_amdgcn_mfma_f32_16x16x32_bf16(afr[3], bb, acc[3][jt], 0, 0, 0);
      }
    }
    __syncthreads();   // MFMA reads done; stage(t3+1) drained; af rebuild safe
    cur ^= 1;
  }

  // ---- epilogue: z = acc + dist*w30 + b3 ; relu ; second layer (256 -> 4)
  float b3v[4][4], w30v[4][4]; float4 w4v[4][4];
  #pragma unroll
  for (int nt = 0; nt < 4; ++nt)
    #pragma unroll
    for (int r = 0; r < 4; ++r) {
      int n = wn*64 + nt*16 + hi*4 + r;
      b3v[nt][r]  = b3[n];
      w30v[nt][r] = W3[n];                 // W3 row 0 = dist weights
      w4v[nt][r]  = *reinterpret_cast<const float4*>(&W4[n*4]);
    }
  #pragma unroll
  for (int jt = 0; jt < 8; ++jt) {
    int j = wj*128 + jt*16 + c15;
    float d = dist_lds[j];
    float4 pe; pe.x=0.f; pe.y=0.f; pe.z=0.f; pe.w=0.f;
    #pragma unroll
    for (int nt = 0; nt < 4; ++nt)
      #pragma unroll
      for (int r = 0; r < 4; ++r) {
        float z  = acc[nt][jt][r] + d*w30v[nt][r] + b3v[nt][r];
        float rz = fmaxf(z, 0.f);
        pe.x += rz*w4v[nt][r].x; pe.y += rz*w4v[nt][r].y;
        pe.z += rz*w4v[nt][r].z; pe.w += rz*w4v[nt][r].w;
      }
    pe.x += __shfl_xor(pe.x, 16); pe.y += __shfl_xor(pe.y, 16);
    pe.z += __shfl_xor(pe.z, 16); pe.w += __shfl_xor(pe.w, 16);
    pe.x += __shfl_xor(pe.x, 32); pe.y += __shfl_xor(pe.y, 32);
    pe.z += __shfl_xor(pe.z, 32); pe.w += __shfl_xor(pe.w, 32);
    if (hi == 0) *reinterpret_cast<float4*>(&u.partial[wn][j][0]) = pe;
  }
  __syncthreads();
  #pragma unroll
  for (int rep = 0; rep < 2; ++rep) {
    int o = rep*512 + tid;
    int j = o >> 2, e = o & 3;
    float v = u.partial[0][j][e] + u.partial[1][j][e]
            + u.partial[2][j][e] + u.partial[3][j][e] + b4[e];
    out[(rowbase*256 + j)*NE + e] = v;
  }
}

extern "C" void kernel_launch(void* const* d_in, const int* in_sizes, int n_in,
                              void* d_out, int out_size, void* d_ws, size_t ws_size,
                              hipStream_t stream) {
  const float* latent    = (const float*)d_in[0];
  const float* positions = (const float*)d_in[1];
  const float* atoms     = (const float*)d_in[2];
  const float* W1 = (const float*)d_in[3];
  const float* b1 = (const float*)d_in[4];
  const float* W2 = (const float*)d_in[5];
  const float* b2 = (const float*)d_in[6];
  const float* W3 = (const float*)d_in[7];
  const float* b3 = (const float*)d_in[8];
  const float* W4 = (const float*)d_in[9];
  const float* b4 = (const float*)d_in[10];
  float* out = (float*)d_out;

  char* ws = (char*)d_ws;
  float*  h_ws   = (float*)ws;                          // 8*256*256*4   = 2,097,152 B
  ushort* G_ws   = (ushort*)(ws + 2097152);             // 8*256*288*2   = 1,179,648 B
  ushort* W3T_ws = (ushort*)(ws + 2097152 + 1179648);   // 256*288*2     =   147,456 B

  hipLaunchKernelGGL(prep_h_kernel, dim3(256), dim3(256), 0, stream,
                     latent, atoms, W1, b1, W2, b2, h_ws, G_ws);
  hipLaunchKernelGGL(prep_w3t_kernel, dim3(256), dim3(256), 0, stream, W3, W3T_ws);
  hipLaunchKernelGGL(edge_main_kernel, dim3(2048), dim3(512), 0, stream,
                     positions, atoms, W3, b3, W4, b4, h_ws, G_ws, W3T_ws, out);
}

// Round 9
// 141.649 us; speedup vs baseline: 1.1434x; 1.1434x over previous
//
#include <hip/hip_runtime.h>

#define DIM 256
#define NA 16
#define NE 4
#define KTOT 288   // 16 atoms + 256 latent + 16 zero pad
#define KC 96      // K per third

typedef __attribute__((ext_vector_type(8))) short short8;
typedef __attribute__((ext_vector_type(4))) float f32x4;

static __device__ __forceinline__ ushort f2bf(float f) {
  union { float f; unsigned int u; } v; v.f = f;
  unsigned int r = (v.u + 0x7FFFu + ((v.u >> 16) & 1u)) >> 16;
  return (ushort)r;
}

static __device__ __forceinline__ float bf2f(ushort s) {
  union { unsigned int u; float f; } v; v.u = ((unsigned int)s) << 16;
  return v.f;
}

static __device__ __forceinline__ unsigned cvtpk(float lo, float hi) {
  unsigned r;
  asm("v_cvt_pk_bf16_f32 %0, %1, %2" : "=v"(r) : "v"(lo), "v"(hi));
  return r;
}

// async global->LDS DMA, 16B per lane; lds dest must be wave-uniform (HW adds lane*16)
static __device__ __forceinline__ void gll16(const void* g, void* l) {
  __builtin_amdgcn_global_load_lds((const __attribute__((address_space(1))) void*)g,
                                   (__attribute__((address_space(3))) void*)l, 16, 0, 0);
}

// ---------------- prep 1: h = relu(latent@W1+b1)@W2+b2 ; build G = [atoms|h|0] bf16
__global__ __launch_bounds__(256) void prep_h_kernel(
    const float* __restrict__ latent, const float* __restrict__ atoms,
    const float* __restrict__ W1, const float* __restrict__ b1,
    const float* __restrict__ W2, const float* __restrict__ b2,
    float* __restrict__ h_out, ushort* __restrict__ G_out) {
  __shared__ float lat[8][DIM];
  __shared__ float t1[8][DIM];
  const int b = blockIdx.x >> 5, i0 = (blockIdx.x & 31) * 8;
  const int k = threadIdx.x;
  #pragma unroll
  for (int r = 0; r < 8; ++r) lat[r][k] = latent[(b*256 + i0 + r) * DIM + k];
  __syncthreads();
  float acc[8];
  #pragma unroll
  for (int r = 0; r < 8; ++r) acc[r] = b1[k];
  for (int c = 0; c < DIM; c += 4) {
    float w0 = W1[(c+0)*DIM + k], w1 = W1[(c+1)*DIM + k];
    float w2 = W1[(c+2)*DIM + k], w3 = W1[(c+3)*DIM + k];
    #pragma unroll
    for (int r = 0; r < 8; ++r) {
      const float4 l4 = *reinterpret_cast<const float4*>(&lat[r][c]);
      acc[r] += l4.x*w0 + l4.y*w1 + l4.z*w2 + l4.w*w3;
    }
  }
  #pragma unroll
  for (int r = 0; r < 8; ++r) t1[r][k] = fmaxf(acc[r], 0.f);
  __syncthreads();
  #pragma unroll
  for (int r = 0; r < 8; ++r) acc[r] = b2[k];
  for (int c = 0; c < DIM; c += 4) {
    float w0 = W2[(c+0)*DIM + k], w1 = W2[(c+1)*DIM + k];
    float w2 = W2[(c+2)*DIM + k], w3 = W2[(c+3)*DIM + k];
    #pragma unroll
    for (int r = 0; r < 8; ++r) {
      const float4 l4 = *reinterpret_cast<const float4*>(&t1[r][c]);
      acc[r] += l4.x*w0 + l4.y*w1 + l4.z*w2 + l4.w*w3;
    }
  }
  #pragma unroll
  for (int r = 0; r < 8; ++r) {
    int row = b*256 + i0 + r;
    h_out[row*DIM + k] = acc[r];
    G_out[row*KTOT + NA + k] = f2bf(acc[r]);
  }
  if (k < NA) {
    #pragma unroll
    for (int r = 0; r < 8; ++r) {
      int row = b*256 + i0 + r;
      G_out[row*KTOT + k] = f2bf(atoms[row*NA + k]);
      G_out[row*KTOT + 272 + k] = 0;
    }
  }
}

// ---------------- prep 2: W3T[k][c] = bf16(W3[1+c][k]) zero-padded to 288
__global__ __launch_bounds__(256) void prep_w3t_kernel(
    const float* __restrict__ W3, ushort* __restrict__ W3T) {
  const int kk = blockIdx.x, c = threadIdx.x;
  W3T[kk*KTOT + c] = (c < 272) ? f2bf(W3[(1+c)*DIM + kk]) : (ushort)0;
  if (c < 32) {
    int c2 = 256 + c;
    W3T[kk*KTOT + c2] = (c2 < 272) ? f2bf(W3[(1+c2)*DIM + kk]) : (ushort)0;
  }
}

// ---------------- main: per (b,i) workgroup; SYMMETRY-EXPLOITING
// Z[i,j,n] = sum_c W3T[n,c]*G[i,c]*G[j,c] is symmetric in i<->j.
// WG i processes only j-tiles >= i's tile (avg 8.5/16 = 47% less work).
// Writes: direct out[i][j] for j>=i; mirror out[j][i] for j>i. Pairs j<i come
// from WG j's mirror -> every element written exactly once (deterministic).
__global__ __attribute__((amdgpu_flat_work_group_size(512,512), amdgpu_waves_per_eu(2,2)))
void edge_main_kernel(
    const float* __restrict__ positions, const float* __restrict__ atoms,
    const float* __restrict__ W3, const float* __restrict__ b3,
    const float* __restrict__ W4, const float* __restrict__ b4,
    const float* __restrict__ h_ws, const ushort* __restrict__ G,
    const ushort* __restrict__ W3T, float* __restrict__ out) {
  __shared__ union UU {
    char bufs[2][49152];          // double-buffered G slab (48KB each, worst case)
    float partial[4][256][4];     // epilogue partials (16KB), used after final barrier
  } u;
  __shared__ char af_lds[49152];  // af slab for current K-third (48KB)
  __shared__ float g_lds[KTOT];
  __shared__ float dist_lds[256];

  const int b = blockIdx.x >> 8, i = blockIdx.x & 255;
  const int tid = threadIdx.x;
  const int lane = tid & 63, w = tid >> 6;
  const int wn = w & 3;           // n-quadrant: 64 cols each
  const int wj = w >> 2;          // j-parity group
  const int c15 = lane & 15, hi = lane >> 4;
  const int rowbase = b*256 + i;

  const int jt0 = i >> 4;               // first j-tile
  const int NT  = 16 - jt0;             // j-tiles processed (1..16)
  const int nst = NT * 12;              // subtiles per K-third
  const int tcnt = (NT - wj + 1) >> 1;  // j-tiles for this wave (wj, wj+2, ...)

  if (tid < KTOT)
    g_lds[tid] = (tid < NA) ? atoms[rowbase*NA + tid]
               : (tid < 272 ? h_ws[rowbase*DIM + (tid - NA)] : 0.f);
  if (tid < 256) {
    const float* pi = &positions[rowbase*3];
    const float* pj = &positions[(b*256 + tid)*3];
    float dx = pi[0]-pj[0], dy = pi[1]-pj[1], dz = pi[2]-pj[2];
    float d2 = dx*dx + dy*dy + dz*dz;
    dist_lds[tid] = d2 > 0.f ? sqrtf(d2) : 0.f;
  }

  // ---- async stage of needed j-slab of one K-third (NT*12 subtiles of 256B)
  auto stage = [&](int bufi, int t3) {
    char* base = u.bufs[bufi];
    #pragma unroll
    for (int ch = 0; ch < 6; ++ch) {
      int st0 = ch*32 + w*4;            // this wave's 4-subtile group (uniform)
      if (st0 >= nst) break;            // wave-uniform early-out
      int st = st0 + hi;
      int rb = st / 12, ks = st - rb*12;
      int row = rowbase - i + (jt0 + rb)*16 + c15;   // b*256 + jtile*16 + c15
      int lim = rowbase - i + 255;
      row = row > lim ? lim : row;      // clamp padding lanes in-bounds
      const ushort* src = &G[(size_t)row * KTOT + t3*KC + ks*8];
      gll16(src, base + st0*256);       // uniform dest; lane data at +lane*16
    }
  };

  f32x4 acc[4][8];
  #pragma unroll
  for (int nt = 0; nt < 4; ++nt)
    #pragma unroll
    for (int t = 0; t < 8; ++t) { acc[nt][t].x=0.f; acc[nt][t].y=0.f; acc[nt][t].z=0.f; acc[nt][t].w=0.f; }

  stage(0, 0);
  __syncthreads();   // g_lds/dist ready + stage(0) DMA drained

  int cur = 0;
  #pragma unroll
  for (int t3 = 0; t3 < 3; ++t3) {
    // ---- build af[t3] cooperatively into LDS: af[n][c] = bf16(g[c]*W3T[n][c])
    #pragma unroll
    for (int s = 0; s < 6; ++s) {
      int id = s*512 + tid;
      int st2 = id >> 4, c15r = id & 15;
      int ntile = st2 / 12, ks = st2 - ntile*12;
      int n = ntile*16 + c15r;
      union { ushort us[8]; short8 s8; } wv;
      wv.s8 = *reinterpret_cast<const short8*>(&W3T[(size_t)n*KTOT + t3*KC + ks*8]);
      const float* gp = &g_lds[t3*KC + ks*8];
      float4 ga = *reinterpret_cast<const float4*>(gp);
      float4 gb = *reinterpret_cast<const float4*>(gp + 4);
      union { unsigned uu[4]; short8 s8; } pk;
      pk.uu[0] = cvtpk(bf2f(wv.us[0])*ga.x, bf2f(wv.us[1])*ga.y);
      pk.uu[1] = cvtpk(bf2f(wv.us[2])*ga.z, bf2f(wv.us[3])*ga.w);
      pk.uu[2] = cvtpk(bf2f(wv.us[4])*gb.x, bf2f(wv.us[5])*gb.y);
      pk.uu[3] = cvtpk(bf2f(wv.us[6])*gb.z, bf2f(wv.us[7])*gb.w);
      *reinterpret_cast<short8*>(&af_lds[st2*256 + c15r*16]) = pk.s8;
    }
    __syncthreads();                 // af[t3] visible (no DMA in flight here)
    if (t3 < 2) stage(cur ^ 1, t3 + 1);   // prefetch next third; drains at NEXT barrier
    // ---- MFMA over this third (guarded compile-time-unrolled t loop)
    const char* bp = u.bufs[cur];
    #pragma unroll
    for (int kc2 = 0; kc2 < 3; ++kc2) {
      short8 afr[4];
      #pragma unroll
      for (int nt = 0; nt < 4; ++nt)
        afr[nt] = *reinterpret_cast<const short8*>(
            &af_lds[((wn*4 + nt)*12 + kc2*4)*256 + lane*16]);
      #pragma unroll
      for (int t = 0; t < 8; ++t) {
        if (t < tcnt) {                // wave-uniform guard
          int strel = (wj + 2*t)*12 + kc2*4;
          short8 bb = *reinterpret_cast<const short8*>(bp + strel*256 + lane*16);
          acc[0][t] = __builtin_amdgcn_mfma_f32_16x16x32_bf16(afr[0], bb, acc[0][t], 0, 0, 0);
          acc[1][t] = __builtin_amdgcn_mfma_f32_16x16x32_bf16(afr[1], bb, acc[1][t], 0, 0, 0);
          acc[2][t] = __builtin_amdgcn_mfma_f32_16x16x32_bf16(afr[2], bb, acc[2][t], 0, 0, 0);
          acc[3][t] = __builtin_amdgcn_mfma_f32_16x16x32_bf16(afr[3], bb, acc[3][t], 0, 0, 0);
        }
      }
    }
    __syncthreads();   // MFMA reads done; stage(t3+1) drained; af rebuild safe
    cur ^= 1;
  }

  __builtin_amdgcn_sched_barrier(0);   // keep epilogue loads OUT of the K-loop region

  // ---- epilogue: z = acc + dist*w30 + b3 ; relu ; second layer (256 -> 4)
  float b3v[4][4], w30v[4][4]; float4 w4v[4][4];
  #pragma unroll
  for (int nt = 0; nt < 4; ++nt)
    #pragma unroll
    for (int r = 0; r < 4; ++r) {
      int n = wn*64 + nt*16 + hi*4 + r;
      b3v[nt][r]  = b3[n];
      w30v[nt][r] = W3[n];                 // W3 row 0 = dist weights
      w4v[nt][r]  = *reinterpret_cast<const float4*>(&W4[n*4]);
    }
  #pragma unroll
  for (int t = 0; t < 8; ++t) {
    if (t < tcnt) {
      int j = (jt0 + wj + 2*t)*16 + c15;
      float d = dist_lds[j];
      float4 pe; pe.x=0.f; pe.y=0.f; pe.z=0.f; pe.w=0.f;
      #pragma unroll
      for (int nt = 0; nt < 4; ++nt)
        #pragma unroll
        for (int r = 0; r < 4; ++r) {
          float z  = acc[nt][t][r] + d*w30v[nt][r] + b3v[nt][r];
          float rz = fmaxf(z, 0.f);
          pe.x += rz*w4v[nt][r].x; pe.y += rz*w4v[nt][r].y;
          pe.z += rz*w4v[nt][r].z; pe.w += rz*w4v[nt][r].w;
        }
      pe.x += __shfl_xor(pe.x, 16); pe.y += __shfl_xor(pe.y, 16);
      pe.z += __shfl_xor(pe.z, 16); pe.w += __shfl_xor(pe.w, 16);
      pe.x += __shfl_xor(pe.x, 32); pe.y += __shfl_xor(pe.y, 32);
      pe.z += __shfl_xor(pe.z, 32); pe.w += __shfl_xor(pe.w, 32);
      if (hi == 0) *reinterpret_cast<float4*>(&u.partial[wn][j][0]) = pe;
    }
  }
  __syncthreads();
  #pragma unroll
  for (int rep = 0; rep < 2; ++rep) {
    int o = rep*512 + tid;
    int j = o >> 2, e = o & 3;
    if (j >= jt0*16) {
      float v = u.partial[0][j][e] + u.partial[1][j][e]
              + u.partial[2][j][e] + u.partial[3][j][e] + b4[e];
      if (j >= i) out[((size_t)rowbase*256 + j)*NE + e] = v;            // upper+diag
      if (j > i)  out[((size_t)(b*256 + j)*256 + i)*NE + e] = v;        // mirror
    }
  }
}

extern "C" void kernel_launch(void* const* d_in, const int* in_sizes, int n_in,
                              void* d_out, int out_size, void* d_ws, size_t ws_size,
                              hipStream_t stream) {
  const float* latent    = (const float*)d_in[0];
  const float* positions = (const float*)d_in[1];
  const float* atoms     = (const float*)d_in[2];
  const float* W1 = (const float*)d_in[3];
  const float* b1 = (const float*)d_in[4];
  const float* W2 = (const float*)d_in[5];
  const float* b2 = (const float*)d_in[6];
  const float* W3 = (const float*)d_in[7];
  const float* b3 = (const float*)d_in[8];
  const float* W4 = (const float*)d_in[9];
  const float* b4 = (const float*)d_in[10];
  float* out = (float*)d_out;

  char* ws = (char*)d_ws;
  float*  h_ws   = (float*)ws;                          // 8*256*256*4   = 2,097,152 B
  ushort* G_ws   = (ushort*)(ws + 2097152);             // 8*256*288*2   = 1,179,648 B
  ushort* W3T_ws = (ushort*)(ws + 2097152 + 1179648);   // 256*288*2     =   147,456 B

  hipLaunchKernelGGL(prep_h_kernel, dim3(256), dim3(256), 0, stream,
                     latent, atoms, W1, b1, W2, b2, h_ws, G_ws);
  hipLaunchKernelGGL(prep_w3t_kernel, dim3(256), dim3(256), 0, stream, W3, W3T_ws);
  hipLaunchKernelGGL(edge_main_kernel, dim3(2048), dim3(512), 0, stream,
                     positions, atoms, W3, b3, W4, b4, h_ws, G_ws, W3T_ws, out);
}